// Round 1
// baseline (184.656 us; speedup 1.0000x reference)
//
#include <hip/hip_runtime.h>
#include <hip/hip_bf16.h>

// ---------------------------------------------------------------------------
// MultiHeadSelfAttention (Swin rel-pos bias), B=64 S=196 D=768 H=12 pd=64
// Pipeline: f2b(x) ; wtrans(W*) ; bias_pre ; GEMM QKV (bf16) ; attn ; GEMM O (f32)
// ---------------------------------------------------------------------------

typedef __bf16 bf16x8 __attribute__((ext_vector_type(8)));
typedef float  f32x4  __attribute__((ext_vector_type(4)));

#define MROWS 12544      // B*S
#define DDIM  768
#define NHEAD 12
#define SEQ   196
#define SEQP  208        // 13*16
#define KSTR  72         // K_lds row stride (bf16) : 144B -> conflict-free-ish
#define VSTR  232        // Vt_lds / P_lds row stride : 464B -> 2-way (free)

static __device__ __forceinline__ f32x4 MFMA(bf16x8 a, bf16x8 b, f32x4 c) {
    return __builtin_amdgcn_mfma_f32_16x16x32_bf16(a, b, c, 0, 0, 0);
}

static __device__ __forceinline__ void gload16(const __bf16* g, __bf16* l) {
    __builtin_amdgcn_global_load_lds(
        (const __attribute__((address_space(1))) void*)(g),
        (__attribute__((address_space(3))) void*)(l),
        16, 0, 0);
}

// ---------------- prep: fp32 -> bf16 (vectorized 8/thread) -----------------
__global__ __launch_bounds__(256) void f2b(const float* __restrict__ in,
                                           __bf16* __restrict__ out) {
    size_t i = ((size_t)blockIdx.x * 256 + threadIdx.x) * 8;
    f32x4 a = *(const f32x4*)&in[i];
    f32x4 b = *(const f32x4*)&in[i + 4];
    bf16x8 o;
    o[0] = (__bf16)a[0]; o[1] = (__bf16)a[1]; o[2] = (__bf16)a[2]; o[3] = (__bf16)a[3];
    o[4] = (__bf16)b[0]; o[5] = (__bf16)b[1]; o[6] = (__bf16)b[2]; o[7] = (__bf16)b[3];
    *(bf16x8*)&out[i] = o;
}

// ---------------- prep: W [k][n] fp32 -> Wt [n][k] bf16 --------------------
__global__ __launch_bounds__(256) void wtrans(const float* __restrict__ W0, const float* __restrict__ W1,
                                              const float* __restrict__ W2, const float* __restrict__ W3,
                                              __bf16* __restrict__ T0, __bf16* __restrict__ T1,
                                              __bf16* __restrict__ T2, __bf16* __restrict__ T3) {
    const float* Ws[4] = {W0, W1, W2, W3};
    __bf16*      Ts[4] = {T0, T1, T2, T3};
    const float* W = Ws[blockIdx.z];
    __bf16*      T = Ts[blockIdx.z];
    __shared__ __bf16 t[32][33];
    int k0 = blockIdx.x * 32, n0 = blockIdx.y * 32;
    int c = threadIdx.x & 31, r = threadIdx.x >> 5;   // r: 0..7
#pragma unroll
    for (int i = 0; i < 4; ++i)
        t[r + i * 8][c] = (__bf16)W[(size_t)(k0 + r + i * 8) * DDIM + n0 + c];
    __syncthreads();
#pragma unroll
    for (int i = 0; i < 4; ++i)
        T[(size_t)(n0 + r + i * 8) * DDIM + k0 + c] = t[c][r + i * 8];
}

// ---------------- prep: bias[h][q][k] = table[rel[q][k]][h] ----------------
__global__ __launch_bounds__(256) void bias_pre(const float* __restrict__ table,
                                                const int* __restrict__ rel,
                                                float* __restrict__ biasH) {
    int i = blockIdx.x * 256 + threadIdx.x;
    if (i < NHEAD * SEQ * SEQ) {
        int h = i / (SEQ * SEQ), qk = i - h * (SEQ * SEQ);
        biasH[i] = table[rel[qk] * NHEAD + h];
    }
}

// ---------------- m97-style bf16 GEMM: C = A[M][K] * Bt[N][K]^T + bias -----
// M=12544, N=768, K=768; tile 128x128, BK=32, 256 thr (4 waves, 64x64 each)
template <typename OutT>
__global__ __launch_bounds__(256) void gemm_bt(const __bf16* __restrict__ A,
                                               const __bf16* __restrict__ Bt0, const __bf16* __restrict__ Bt1,
                                               const __bf16* __restrict__ Bt2,
                                               const float* __restrict__ b0, const float* __restrict__ b1,
                                               const float* __restrict__ b2,
                                               OutT* __restrict__ C0, OutT* __restrict__ C1,
                                               OutT* __restrict__ C2) {
    const __bf16* Bts[3] = {Bt0, Bt1, Bt2};
    const float*  bs[3]  = {b0, b1, b2};
    OutT*         Cs[3]  = {C0, C1, C2};
    const __bf16* Bt = Bts[blockIdx.z];
    const float*  bias = bs[blockIdx.z];
    OutT*         C = Cs[blockIdx.z];

    __shared__ __bf16 Asm[128 * 32];
    __shared__ __bf16 Bsm[128 * 32];

    const int tid = threadIdx.x, w = tid >> 6, l = tid & 63;
    const int lr = l & 15, lg = l >> 4;
    const int m0 = blockIdx.x * 128, n0 = blockIdx.y * 128;
    const int wr = (w >> 1) * 64, wc = (w & 1) * 64;

    // staging addresses: chunk = w*2+i covers rows chunk*16 + l/4, cols (l&3)*8
    const __bf16* ga = A  + (size_t)(m0 + w * 32 + (l >> 2)) * DDIM + (l & 3) * 8;
    const __bf16* gb = Bt + (size_t)(n0 + w * 32 + (l >> 2)) * DDIM + (l & 3) * 8;
    __bf16* lA = &Asm[w * 1024];
    __bf16* lB = &Bsm[w * 1024];

    f32x4 zf = {0.f, 0.f, 0.f, 0.f};
    f32x4 acc[4][4];
#pragma unroll
    for (int i = 0; i < 4; ++i)
#pragma unroll
        for (int j = 0; j < 4; ++j) acc[i][j] = zf;

    for (int kt = 0; kt < DDIM / 32; ++kt) {
        const int ko = kt * 32;
        __syncthreads();                       // previous compute done
        gload16(ga + ko, lA);
        gload16(ga + ko + 16 * DDIM, lA + 512);
        gload16(gb + ko, lB);
        gload16(gb + ko + 16 * DDIM, lB + 512);
        __syncthreads();                       // tiles ready (vmcnt drained)

        bf16x8 af[4], bf_[4];
#pragma unroll
        for (int t = 0; t < 4; ++t)
            af[t] = *(const bf16x8*)&Asm[(wr + t * 16 + lr) * 32 + lg * 8];
#pragma unroll
        for (int t = 0; t < 4; ++t)
            bf_[t] = *(const bf16x8*)&Bsm[(wc + t * 16 + lr) * 32 + lg * 8];
#pragma unroll
        for (int mt = 0; mt < 4; ++mt)
#pragma unroll
            for (int nt = 0; nt < 4; ++nt)
                acc[mt][nt] = MFMA(af[mt], bf_[nt], acc[mt][nt]);
    }

#pragma unroll
    for (int nt = 0; nt < 4; ++nt) {
        const int col = n0 + wc + nt * 16 + lr;
        const float bb = bias[col];
#pragma unroll
        for (int mt = 0; mt < 4; ++mt) {
            const int row = m0 + wr + mt * 16 + lg * 4;
#pragma unroll
            for (int r = 0; r < 4; ++r)
                C[(size_t)(row + r) * DDIM + col] = (OutT)(acc[mt][nt][r] + bb);
        }
    }
}

// ---------------- fused attention: one block per (b,h) ---------------------
__global__ __launch_bounds__(256) void attn_kernel(const __bf16* __restrict__ Qg,
                                                   const __bf16* __restrict__ Kg,
                                                   const __bf16* __restrict__ Vg,
                                                   const float* __restrict__ biasH,
                                                   __bf16* __restrict__ Og) {
    __shared__ __bf16 Ksm[SEQP * KSTR];        // [208][72]
    __shared__ __bf16 Vts[64 * VSTR];          // [64][232]  (V transposed: [d][kk])
    __shared__ __bf16 Psm[4 * 16 * VSTR];      // per-wave [16][232]

    const int b = blockIdx.x, h = blockIdx.y;
    const int tid = threadIdx.x, w = tid >> 6, l = tid & 63;
    const int lr = l & 15, lg = l >> 4;
    const size_t base = (size_t)(b * SEQ) * DDIM + h * 64;
    const __bf16* Kb = Kg + base;
    const __bf16* Vb = Vg + base;
    const __bf16* Qb = Qg + base;
    const float*  bh = biasH + (size_t)h * (SEQ * SEQ);

    // stage K rows 0..195 (8 bf16 / chunk)
    for (int c = tid; c < SEQ * 8; c += 256) {
        int kk = c >> 3, d8 = (c & 7) << 3;
        *(bf16x8*)&Ksm[kk * KSTR + d8] = *(const bf16x8*)&Kb[(size_t)kk * DDIM + d8];
    }
    // zero K pad rows 196..207
    for (int c = tid; c < 12 * 9; c += 256) {
        int kk = SEQ + c / 9, d8 = (c % 9) * 8;
        *(uint4*)&Ksm[kk * KSTR + d8] = make_uint4(0u, 0u, 0u, 0u);
    }
    // stage V transposed
    for (int c = tid; c < SEQ * 8; c += 256) {
        int kk = c >> 3, d8 = (c & 7) << 3;
        bf16x8 vv = *(const bf16x8*)&Vb[(size_t)kk * DDIM + d8];
#pragma unroll
        for (int j = 0; j < 8; ++j) Vts[(d8 + j) * VSTR + kk] = vv[j];
    }
    // zero Vt cols 196..223
    for (int c = tid; c < 64 * 28; c += 256)
        Vts[(c / 28) * VSTR + SEQ + (c % 28)] = (__bf16)0.f;
    // zero own-wave P cols 208..223
    for (int c = l; c < 256; c += 64)
        Psm[w * 16 * VSTR + (c >> 4) * VSTR + SEQP + (c & 15)] = (__bf16)0.f;
    __syncthreads();

    __bf16* Pw = &Psm[w * 16 * VSTR];

    for (int qt = w; qt < 13; qt += 4) {
        const int q0 = qt * 16;
        const int qrow = min(q0 + lr, SEQ - 1);
        bf16x8 aq0 = *(const bf16x8*)&Qb[(size_t)qrow * DDIM + lg * 8];
        bf16x8 aq1 = *(const bf16x8*)&Qb[(size_t)qrow * DDIM + 32 + lg * 8];

        f32x4 sc[13];
#pragma unroll
        for (int nt = 0; nt < 13; ++nt) {
            f32x4 a = {0.f, 0.f, 0.f, 0.f};
            bf16x8 bk0 = *(const bf16x8*)&Ksm[(nt * 16 + lr) * KSTR + lg * 8];
            bf16x8 bk1 = *(const bf16x8*)&Ksm[(nt * 16 + lr) * KSTR + 32 + lg * 8];
            a = MFMA(aq0, bk0, a);
            a = MFMA(aq1, bk1, a);
            sc[nt] = a;
        }

        // scale + bias + mask, track row max (rows = q0 + lg*4 + r, col = nt*16+lr)
        float mx[4] = {-1e30f, -1e30f, -1e30f, -1e30f};
#pragma unroll
        for (int nt = 0; nt < 13; ++nt) {
            const int col = nt * 16 + lr;
            const bool valid = (nt < 12) || (lr < 4);       // col < 196
            const float* bp = bh + col;
#pragma unroll
            for (int r = 0; r < 4; ++r) {
                const int row = min(q0 + lg * 4 + r, SEQ - 1);
                float v = valid ? (sc[nt][r] * 0.125f + bp[(size_t)row * SEQ]) : -1e30f;
                sc[nt][r] = v;
                mx[r] = fmaxf(mx[r], v);
            }
        }
#pragma unroll
        for (int m = 1; m < 16; m <<= 1)
#pragma unroll
            for (int r = 0; r < 4; ++r) mx[r] = fmaxf(mx[r], __shfl_xor(mx[r], m));

        float sum[4] = {0.f, 0.f, 0.f, 0.f};
#pragma unroll
        for (int nt = 0; nt < 13; ++nt)
#pragma unroll
            for (int r = 0; r < 4; ++r) {
                float p = __expf(sc[nt][r] - mx[r]);
                sum[r] += p;
                sc[nt][r] = p;
            }
#pragma unroll
        for (int m = 1; m < 16; m <<= 1)
#pragma unroll
            for (int r = 0; r < 4; ++r) sum[r] += __shfl_xor(sum[r], m);

        // write P (bf16) to own-wave LDS buffer
#pragma unroll
        for (int nt = 0; nt < 13; ++nt)
#pragma unroll
            for (int r = 0; r < 4; ++r)
                Pw[(lg * 4 + r) * VSTR + nt * 16 + lr] = (__bf16)sc[nt][r];

        // PV: out[16x64] = P[16x224] * V[224x64]
        f32x4 oa[4];
#pragma unroll
        for (int i = 0; i < 4; ++i) oa[i] = (f32x4){0.f, 0.f, 0.f, 0.f};
#pragma unroll
        for (int kt = 0; kt < 7; ++kt) {
            bf16x8 ap = *(const bf16x8*)&Pw[lr * VSTR + kt * 32 + lg * 8];
#pragma unroll
            for (int nt = 0; nt < 4; ++nt) {
                bf16x8 bv = *(const bf16x8*)&Vts[(nt * 16 + lr) * VSTR + kt * 32 + lg * 8];
                oa[nt] = MFMA(ap, bv, oa[nt]);
            }
        }

        float inv[4];
#pragma unroll
        for (int r = 0; r < 4; ++r) inv[r] = 1.f / sum[r];
#pragma unroll
        for (int nt = 0; nt < 4; ++nt)
#pragma unroll
            for (int r = 0; r < 4; ++r) {
                const int row = q0 + lg * 4 + r;
                if (row < SEQ)
                    Og[(size_t)(b * SEQ + row) * DDIM + h * 64 + nt * 16 + lr] =
                        (__bf16)(oa[nt][r] * inv[r]);
            }
    }
}

// ---------------------------------------------------------------------------
extern "C" void kernel_launch(void* const* d_in, const int* in_sizes, int n_in,
                              void* d_out, int out_size, void* d_ws, size_t ws_size,
                              hipStream_t stream) {
    const float* x     = (const float*)d_in[0];
    const float* Wq    = (const float*)d_in[1];
    const float* bq    = (const float*)d_in[2];
    const float* Wk    = (const float*)d_in[3];
    const float* bk    = (const float*)d_in[4];
    const float* Wv    = (const float*)d_in[5];
    const float* bv    = (const float*)d_in[6];
    const float* Wo    = (const float*)d_in[7];
    const float* bo    = (const float*)d_in[8];
    const float* table = (const float*)d_in[9];
    const int*   rel   = (const int*)d_in[10];
    float* out = (float*)d_out;

    char* ws = (char*)d_ws;
    auto alloc = [&](size_t bytes) {
        char* p = ws;
        ws += (bytes + 255) & ~(size_t)255;
        return p;
    };
    const size_t mat = (size_t)MROWS * DDIM * sizeof(__bf16);
    __bf16* xb = (__bf16*)alloc(mat);
    __bf16* Tq = (__bf16*)alloc((size_t)DDIM * DDIM * 2);
    __bf16* Tk = (__bf16*)alloc((size_t)DDIM * DDIM * 2);
    __bf16* Tv = (__bf16*)alloc((size_t)DDIM * DDIM * 2);
    __bf16* To = (__bf16*)alloc((size_t)DDIM * DDIM * 2);
    __bf16* Qb = (__bf16*)alloc(mat);
    __bf16* Kb = (__bf16*)alloc(mat);
    __bf16* Vb = (__bf16*)alloc(mat);
    __bf16* AO = (__bf16*)alloc(mat);
    float* biasH = (float*)alloc((size_t)NHEAD * SEQ * SEQ * 4);

    f2b<<<dim3(4704), 256, 0, stream>>>(x, xb);                       // 12544*768/8/256
    wtrans<<<dim3(24, 24, 4), 256, 0, stream>>>(Wq, Wk, Wv, Wo, Tq, Tk, Tv, To);
    bias_pre<<<dim3(1801), 256, 0, stream>>>(table, rel, biasH);
    gemm_bt<__bf16><<<dim3(98, 6, 3), 256, 0, stream>>>(xb, Tq, Tk, Tv, bq, bk, bv, Qb, Kb, Vb);
    attn_kernel<<<dim3(64, 12), 256, 0, stream>>>(Qb, Kb, Vb, biasH, AO);
    gemm_bt<float><<<dim3(98, 6, 1), 256, 0, stream>>>(AO, To, To, To, bo, bo, bo, out, out, out);
}